// Round 4
// baseline (335.511 us; speedup 1.0000x reference)
//
#include <hip/hip_runtime.h>
#include <math.h>

typedef _Float16 half8 __attribute__((ext_vector_type(8)));
typedef float f32x4 __attribute__((ext_vector_type(4)));

#define BTOT   65536
#define DDIM   256
#define KC     1024

// ---------------- ||e_k||^2 ----------------
__global__ void vq_e2(const float* __restrict__ embed, float* __restrict__ e2g) {
    int gt = blockIdx.x * blockDim.x + threadIdx.x;
    int k = gt >> 6;
    int lane = gt & 63;
    float4 v = *(const float4*)(embed + (size_t)k * DDIM + lane * 4);
    float s = v.x * v.x + v.y * v.y + v.z * v.z + v.w * v.w;
    #pragma unroll
    for (int off = 1; off < 64; off <<= 1) s += __shfl_xor(s, off);
    if (lane == 0) e2g[k] = s;
}

// ---------------- prep: embed -> fp16 hi/lo fragment-ordered image --------
// chunks of 1024B: chunk = (g*8 + kc)*2 + p   (g = col-group c>>4, kc = k>>5,
// p: 0=hi 1=lo). Within chunk, lane l's 16B at l*16 holds col (l&15), k-slot
// (l>>4): element (c,k) for c&15, s=(k&31)>>3 stored at (c&15)*16 + s*256.
__global__ void vq_prep(const float* __restrict__ embed, char* __restrict__ wsB) {
    int id = blockIdx.x * 256 + threadIdx.x;   // 32768 total
    int c  = id >> 5;          // 0..1023
    int kc = (id >> 2) & 7;    // 0..7
    int s  = id & 3;           // 0..3
    const float* src = embed + (size_t)c * DDIM + kc * 32 + s * 8;
    half8 hi, lo;
    #pragma unroll
    for (int j = 0; j < 8; ++j) {
        float xv = src[j];
        _Float16 hh = (_Float16)xv;
        hi[j] = hh;
        lo[j] = (_Float16)(xv - (float)hh);
    }
    int g = c >> 4;
    size_t base = ((size_t)((g * 8 + kc) * 2) << 10) + (c & 15) * 16 + s * 256;
    *(half8*)(wsB + base) = hi;
    *(half8*)(wsB + base + 1024) = lo;
}

// ---------------- main fused MFMA GEMM + softmax/argmax ----------------
// 1024 threads (16 waves); block owns 64 rows x all 1024 cols; wave w owns
// cols [w*64, w*64+64). A (z) fp16 hi/lo in LDS; B streamed global->reg from
// the L2-resident image. NO barriers in the K-loop.
__global__ __launch_bounds__(1024, 4)
void vq_main(const float* __restrict__ z, const char* __restrict__ wsB,
             const float* __restrict__ e2g, float* __restrict__ psum_g,
             float* __restrict__ counts_g, float* __restrict__ distsum_g,
             float* __restrict__ codes_f_out)
{
    // A: [kc(8)][p(2)][row(64)][slot(4, xor-swizzled)] = 64KB
    __shared__ __align__(16) char ldsA[65536];
    // epilogue aliases (ldsA dead after K-loop):
    float* lmax     = (float*)ldsA;               // [64][16] 4KB
    int*   larg     = (int*)(ldsA + 4096);        // [64][16] 4KB
    float* lsum     = (float*)(ldsA + 8192);      // [64][16] 4KB
    float* rowM     = (float*)(ldsA + 12288);     // [64]
    float* rowInv   = (float*)(ldsA + 12544);     // [64]
    float* psum_lds = (float*)(ldsA + 16384);     // [1024] 4KB

    const int tid  = threadIdx.x;
    const int w    = tid >> 6;
    const int lane = tid & 63;
    const int row0 = blockIdx.x * 64;
    // A fragment base: row=(lane&15), k-slot=(lane>>4) xor-swizzled
    const int aBase = (lane & 15) * 64 + (((lane >> 4) ^ ((lane >> 1) & 3)) << 4);

    // ---- A staging: 64 rows of z -> fp16 hi/lo swizzled in LDS ----
    {
        const int ar = tid >> 4;     // row 0..63 (wave w: rows 4w..4w+3)
        const int kp = tid & 15;     // 16-float k-part
        const float* src = z + (size_t)(row0 + ar) * DDIM + kp * 16;
        float x[16];
        #pragma unroll
        for (int j = 0; j < 4; ++j) {
            float4 v = ((const float4*)src)[j];
            x[4*j] = v.x; x[4*j+1] = v.y; x[4*j+2] = v.z; x[4*j+3] = v.w;
        }
        float zsq = 0.f;
        #pragma unroll
        for (int j = 0; j < 16; ++j) zsq = fmaf(x[j], x[j], zsq);
        #pragma unroll
        for (int off = 1; off < 64; off <<= 1) zsq += __shfl_xor(zsq, off);
        if (lane == 0) atomicAdd(distsum_g, zsq);   // Σ||z||^2 (4 rows/wave)
        const int kc = kp >> 1;
        #pragma unroll
        for (int jj = 0; jj < 2; ++jj) {
            int s = (kp & 1) * 2 + jj;
            half8 hi, lo;
            #pragma unroll
            for (int j = 0; j < 8; ++j) {
                float xv = x[jj * 8 + j];
                _Float16 hh = (_Float16)xv;
                hi[j] = hh;
                lo[j] = (_Float16)(xv - (float)hh);
            }
            int off = kc * 8192 + ar * 64 + ((s ^ ((ar >> 1) & 3)) << 4);
            *(half8*)(ldsA + off) = hi;            // p=0
            *(half8*)(ldsA + 4096 + off) = lo;     // p=1
        }
    }
    __syncthreads();

    f32x4 acc[4][4];
    #pragma unroll
    for (int rt = 0; rt < 4; ++rt)
        #pragma unroll
        for (int cg = 0; cg < 4; ++cg)
            acc[rt][cg] = (f32x4){0.f, 0.f, 0.f, 0.f};

    // ---- K-loop: barrier-free; B streamed from L2-resident image ----
    for (int kc = 0; kc < 8; ++kc) {
        half8 aHi[4], aLo[4];
        #pragma unroll
        for (int rt = 0; rt < 4; ++rt) {
            aHi[rt] = *(const half8*)(ldsA + kc * 8192 + rt * 1024 + aBase);
            aLo[rt] = *(const half8*)(ldsA + kc * 8192 + 4096 + rt * 1024 + aBase);
        }
        #pragma unroll
        for (int cg = 0; cg < 4; ++cg) {
            const char* bp = wsB + ((size_t)(((w * 4 + cg) * 8 + kc) * 2) << 10)
                                 + (lane << 4);
            half8 bHi = *(const half8*)bp;
            half8 bLo = *(const half8*)(bp + 1024);
            // 3 independent rt-sweeps: dependency distance 4 per acc element;
            // per-acc product order identical to verified R2/R3 numerics.
            #pragma unroll
            for (int rt = 0; rt < 4; ++rt)
                acc[rt][cg] = __builtin_amdgcn_mfma_f32_16x16x32_f16(
                    aHi[rt], bHi, acc[rt][cg], 0, 0, 0);
            #pragma unroll
            for (int rt = 0; rt < 4; ++rt)
                acc[rt][cg] = __builtin_amdgcn_mfma_f32_16x16x32_f16(
                    aLo[rt], bHi, acc[rt][cg], 0, 0, 0);
            #pragma unroll
            for (int rt = 0; rt < 4; ++rt)
                acc[rt][cg] = __builtin_amdgcn_mfma_f32_16x16x32_f16(
                    aHi[rt], bLo, acc[rt][cg], 0, 0, 0);
        }
    }
    __syncthreads();   // ldsA dead -> reuse for epilogue

    // ---- epilogue ----
    // wave w cols: cg -> w*64 + cg*16 + (lane&15); C/D row = rt*16+(lane>>4)*4+i
    int colv[4];
    float e2v[4];
    #pragma unroll
    for (int cg = 0; cg < 4; ++cg) {
        colv[cg] = w * 64 + cg * 16 + (lane & 15);
        e2v[cg] = e2g[colv[cg]];
    }
    psum_lds[tid] = 0.f;
    // pass 1: per-wave local max/argmax per row
    #pragma unroll
    for (int rt = 0; rt < 4; ++rt) {
        #pragma unroll
        for (int i = 0; i < 4; ++i) {
            float m = -INFINITY; int am = 0x7fffffff;
            #pragma unroll
            for (int cg = 0; cg < 4; ++cg) {
                float l = fmaf(2.f, acc[rt][cg][i], -e2v[cg]);
                if (l > m) { m = l; am = colv[cg]; }
            }
            #pragma unroll
            for (int off = 1; off < 16; off <<= 1) {
                float om = __shfl_xor(m, off);
                int   oa = __shfl_xor(am, off);
                if (om > m || (om == m && oa < am)) { m = om; am = oa; }
            }
            if ((lane & 15) == 0) {
                int r = rt * 16 + ((lane >> 4) << 2) + i;
                lmax[r * 16 + w] = m; larg[r * 16 + w] = am;
            }
        }
    }
    __syncthreads();
    // pass 2: cross-wave reduce; codes, counts, -Σ(max logit)
    if (tid < 64) {
        float M = -INFINITY; int A = 0x7fffffff;
        #pragma unroll
        for (int ww = 0; ww < 16; ++ww) {
            float mm = lmax[tid * 16 + ww]; int aa = larg[tid * 16 + ww];
            if (mm > M || (mm == M && aa < A)) { M = mm; A = aa; }
        }
        rowM[tid] = M;
        codes_f_out[row0 + tid] = (float)A;
        atomicAdd(&counts_g[A], 1.0f);
        float negm = -M;
        #pragma unroll
        for (int off = 1; off < 64; off <<= 1) negm += __shfl_xor(negm, off);
        if (tid == 0) atomicAdd(distsum_g, negm);
    }
    __syncthreads();
    // pass 3: exp and per-wave row sums
    #pragma unroll
    for (int rt = 0; rt < 4; ++rt) {
        #pragma unroll
        for (int i = 0; i < 4; ++i) {
            const int r = rt * 16 + ((lane >> 4) << 2) + i;
            float M = rowM[r];
            float ss = 0.f;
            #pragma unroll
            for (int cg = 0; cg < 4; ++cg) {
                float e = __expf(fmaf(2.f, acc[rt][cg][i], -e2v[cg]) - M);
                acc[rt][cg][i] = e;
                ss += e;
            }
            #pragma unroll
            for (int off = 1; off < 16; off <<= 1) ss += __shfl_xor(ss, off);
            if ((lane & 15) == 0) lsum[r * 16 + w] = ss;
        }
    }
    __syncthreads();
    // pass 4: row denominators
    if (tid < 64) {
        float S = 0.f;
        #pragma unroll
        for (int ww = 0; ww < 16; ++ww) S += lsum[tid * 16 + ww];
        rowInv[tid] = 1.0f / S;
    }
    __syncthreads();
    // pass 5: per-code prob sums
    #pragma unroll
    for (int cg = 0; cg < 4; ++cg) {
        float cp = 0.f;
        #pragma unroll
        for (int rt = 0; rt < 4; ++rt)
            #pragma unroll
            for (int i = 0; i < 4; ++i)
                cp = fmaf(acc[rt][cg][i], rowInv[rt * 16 + ((lane >> 4) << 2) + i], cp);
        atomicAdd(&psum_lds[colv[cg]], cp);
    }
    __syncthreads();
    atomicAdd(&psum_g[tid], psum_lds[tid]);
}

// ---------------- gather z_q = embed[codes] ----------------
__global__ void vq_gather(const float* __restrict__ embed,
                          const float* __restrict__ codes_f,
                          float* __restrict__ outq)
{
    int idx = blockIdx.x * 256 + threadIdx.x;   // [0, 4194304)
    int b = idx >> 6;
    int c = (int)codes_f[b];
    ((float4*)outq)[idx] = ((const float4*)embed)[(c << 6) + (idx & 63)];
}

// ---------------- finalize scalars ----------------
__global__ void vq_finalize(const float* __restrict__ psum_g,
                            const float* __restrict__ counts_g,
                            const float* __restrict__ distsum_g,
                            float* __restrict__ out_s)
{
    __shared__ float s1[16], s2[16];
    int tid = threadIdx.x;           // 1024 threads
    float a = psum_g[tid] * (1.0f / 65536.0f);
    float e1 = -a * logf(a + 1e-10f);
    float h = counts_g[tid] * (1.0f / 65536.0f);
    float e2 = -h * logf(h + 1e-10f);
    #pragma unroll
    for (int off = 1; off < 64; off <<= 1) {
        e1 += __shfl_xor(e1, off);
        e2 += __shfl_xor(e2, off);
    }
    int w = tid >> 6, lane = tid & 63;
    if (lane == 0) { s1[w] = e1; s2[w] = e2; }
    __syncthreads();
    if (tid == 0) {
        float E1 = 0.0f, E2 = 0.0f;
        #pragma unroll
        for (int i = 0; i < 16; ++i) { E1 += s1[i]; E2 += s2[i]; }
        float commit = distsum_g[0] * (1.0f / 16777216.0f);
        out_s[0] = commit;
        out_s[1] = commit;
        out_s[2] = -E1 / 6.9314718055994531f;
        out_s[3] = E1;
        out_s[4] = __expf(E2);
    }
}

extern "C" void kernel_launch(void* const* d_in, const int* in_sizes, int n_in,
                              void* d_out, int out_size, void* d_ws, size_t ws_size,
                              hipStream_t stream) {
    const float* z     = (const float*)d_in[0];
    const float* embed = (const float*)d_in[1];

    float* out      = (float*)d_out;
    float* zq_out   = out;                  // 16777216
    float* codes_f  = out + 16777216;       // 65536
    float* scalars  = out + 16842752;       // 5

    float* ws        = (float*)d_ws;
    float* psum_g    = ws;                  // 1024
    float* counts_g  = ws + 1024;           // 1024
    float* e2g       = ws + 2048;           // 1024
    float* distsum_g = ws + 3072;           // 1
    char*  wsB       = (char*)d_ws + 16384; // 1 MB fp16 image

    hipMemsetAsync(d_ws, 0, 3080 * sizeof(float), stream);
    vq_prep<<<128, 256, 0, stream>>>(embed, wsB);
    vq_e2<<<256, 256, 0, stream>>>(embed, e2g);
    vq_main<<<BTOT / 64, 1024, 0, stream>>>(z, wsB, e2g, psum_g, counts_g,
                                            distsum_g, codes_f);
    vq_gather<<<4194304 / 256, 256, 0, stream>>>(embed, codes_f, zq_out);
    vq_finalize<<<1, 1024, 0, stream>>>(psum_g, counts_g, distsum_g, scalars);
}